// Round 5
// baseline (430.895 us; speedup 1.0000x reference)
//
#include <hip/hip_runtime.h>
#include <stdint.h>

#define S_LEN 1024
#define HDIM  4096
#define NHEAD 32
#define DHEAD 128
#define BATCH 2
#define MTOK  (BATCH * S_LEN)   // 2048

typedef __attribute__((ext_vector_type(4))) int   i32x4;
typedef __attribute__((ext_vector_type(4))) float f32x4;
typedef __attribute__((ext_vector_type(8))) short bf16x8;

#define GLOBAL_AS __attribute__((address_space(1)))
#define LDS_AS    __attribute__((address_space(3)))

__device__ __forceinline__ void gl2lds16(const void* g, void* l) {
  __builtin_amdgcn_global_load_lds((const GLOBAL_AS unsigned int*)(g),
                                   (LDS_AS unsigned int*)(l), 16, 0, 0);
}

// float -> bf16 bits, round-to-nearest-even (exact for small ints)
__device__ __forceinline__ unsigned short f2bf(float f) {
  unsigned int u = __float_as_uint(f);
  unsigned int r = (u + 0x7fffu + ((u >> 16) & 1u)) >> 16;
  return (unsigned short)r;
}

// -------- per-row symmetric fake-quant: x (row of 4096 f32) -> int8 + scale --------
__global__ __launch_bounds__(256) void rowquant_kernel(
    const float* __restrict__ x, int8_t* __restrict__ q,
    float* __restrict__ scales, float qmax, float clipLo)
{
  const int row = blockIdx.x;
  const int t = threadIdx.x;
  const float* xr = x + (size_t)row * HDIM;
  float4 v[4];
  float am = 0.f;
#pragma unroll
  for (int i = 0; i < 4; ++i) {
    v[i] = ((const float4*)xr)[t + 256 * i];
    am = fmaxf(am, fmaxf(fmaxf(fabsf(v[i].x), fabsf(v[i].y)),
                         fmaxf(fabsf(v[i].z), fabsf(v[i].w))));
  }
#pragma unroll
  for (int off = 32; off > 0; off >>= 1) am = fmaxf(am, __shfl_down(am, off));
  __shared__ float wred[4];
  if ((t & 63) == 0) wred[t >> 6] = am;
  __syncthreads();
  const float m = fmaxf(fmaxf(wred[0], wred[1]), fmaxf(wred[2], wred[3]));
  const float scale = fmaxf(m / qmax, 1e-8f);
  if (t == 0) scales[row] = scale;
  int* qo = (int*)(q + (size_t)row * HDIM);
#pragma unroll
  for (int i = 0; i < 4; ++i) {
    int b0 = (int)fminf(fmaxf(rintf(v[i].x / scale), clipLo), qmax);
    int b1 = (int)fminf(fmaxf(rintf(v[i].y / scale), clipLo), qmax);
    int b2 = (int)fminf(fmaxf(rintf(v[i].z / scale), clipLo), qmax);
    int b3 = (int)fminf(fmaxf(rintf(v[i].w / scale), clipLo), qmax);
    qo[t + 256 * i] = (b0 & 0xff) | ((b1 & 0xff) << 8) | ((b2 & 0xff) << 16) | ((b3 & 0xff) << 24);
  }
}

// ======== i8 MFMA GEMM v2: 128x256 tile, BK=128B, 8 waves, 2-phase dbuf ========
// C[m,n] = sa[m]*sb[n]*dot(A8[m,:4096], B8[n,:4096])  (exact integer MFMA)
#define BM 128
#define BN 256
#define BKB 128

__global__ __launch_bounds__(512, 1) void gemm_i8_mfma2_kernel(
    const int8_t* __restrict__ A, const float* __restrict__ sa,
    const int8_t* __restrict__ Bw, const float* __restrict__ sb,
    float* __restrict__ C)
{
  __shared__ __align__(16) int8_t asB[2][BM * BKB];   // 2 x 16 KB
  __shared__ __align__(16) int8_t bsB[2][BN * BKB];   // 2 x 32 KB

  // XCD-chunked bijective swizzle over 256 blocks (32/XCD), bn-major within XCD
  const int flat = blockIdx.y * gridDim.x + blockIdx.x;
  const int nf = (flat & 7) * 32 + (flat >> 3);
  const int bxn = nf >> 4, byn = nf & 15;     // 16 n-tiles, 16 m-tiles
  const int bm = byn * BM, bn = bxn * BN;

  const int tid = threadIdx.x;
  const int w = tid >> 6, l = tid & 63;
  const int l15 = l & 15, lg = l >> 4;
  const int lr = l >> 3, g7 = l & 7;
  const int wm = w >> 2, wn = w & 3;
  const int m0 = wm * 64, n0 = wn * 64;

  // staging source: pre-swizzled global slot so linear LDS + XOR read is conflict-free
  const int8_t* aSrc = A + (size_t)bm * HDIM + ((g7 ^ lr) << 4);
  const int8_t* bSrc = Bw + (size_t)bn * HDIM + ((g7 ^ lr) << 4);

  i32x4 acc[4][4];
#pragma unroll
  for (int i = 0; i < 4; ++i)
#pragma unroll
    for (int j = 0; j < 4; ++j) acc[i][j] = (i32x4){0, 0, 0, 0};

  const int NT = HDIM / BKB;   // 32

  // ---- prologue: stage tile 0 ----
#pragma unroll
  for (int i = 0; i < 2; ++i) {
    const int r0 = (w * 2 + i) * 8;
    gl2lds16(aSrc + (size_t)(r0 + lr) * HDIM, asB[0] + r0 * BKB);
  }
#pragma unroll
  for (int i = 0; i < 4; ++i) {
    const int r0 = (w * 4 + i) * 8;
    gl2lds16(bSrc + (size_t)(r0 + lr) * HDIM, bsB[0] + r0 * BKB);
  }
  __syncthreads();

  int cur = 0;
  for (int t = 0; t < NT; ++t) {
    // ---- issue next tile's staging (overlaps with MFMA below) ----
    if (t + 1 < NT) {
      const int k = (t + 1) * BKB;
#pragma unroll
      for (int i = 0; i < 2; ++i) {
        const int r0 = (w * 2 + i) * 8;
        gl2lds16(aSrc + (size_t)(r0 + lr) * HDIM + k, asB[cur ^ 1] + r0 * BKB);
      }
#pragma unroll
      for (int i = 0; i < 4; ++i) {
        const int r0 = (w * 4 + i) * 8;
        gl2lds16(bSrc + (size_t)(r0 + lr) * HDIM + k, bsB[cur ^ 1] + r0 * BKB);
      }
    }
    // ---- compute current tile ----
    __builtin_amdgcn_s_setprio(1);
#pragma unroll
    for (int kk = 0; kk < 2; ++kk) {
      i32x4 aF[4], bF[4];
#pragma unroll
      for (int i = 0; i < 4; ++i) {
        const int R = m0 + i * 16 + l15;
        aF[i] = *(const i32x4*)(asB[cur] + R * BKB + ((((kk << 2) + lg) ^ (R & 7)) << 4));
      }
#pragma unroll
      for (int j = 0; j < 4; ++j) {
        const int R = n0 + j * 16 + l15;
        bF[j] = *(const i32x4*)(bsB[cur] + R * BKB + ((((kk << 2) + lg) ^ (R & 7)) << 4));
      }
#pragma unroll
      for (int i = 0; i < 4; ++i)
#pragma unroll
        for (int j = 0; j < 4; ++j)
          acc[i][j] = __builtin_amdgcn_mfma_i32_16x16x64_i8(aF[i], bF[j], acc[i][j], 0, 0, 0);
    }
    __builtin_amdgcn_s_setprio(0);
    __syncthreads();   // drains next-tile loads (vmcnt 0) + syncs buffer swap
    cur ^= 1;
  }

  // ---- epilogue ----
  float sbr[4];
#pragma unroll
  for (int j = 0; j < 4; ++j) sbr[j] = sb[bn + n0 + j * 16 + l15];
#pragma unroll
  for (int i = 0; i < 4; ++i) {
#pragma unroll
    for (int r = 0; r < 4; ++r) {
      const int m = bm + m0 + i * 16 + lg * 4 + r;
      const float sm = sa[m];
      float* cp = C + (size_t)m * HDIM + bn + n0 + l15;
#pragma unroll
      for (int j = 0; j < 4; ++j)
        cp[j * 16] = sm * sbr[j] * (float)acc[i][j][r];
    }
  }
}

// -------- RoPE + per-(b,s,h) fake-quant8 for Q,K; layout [bh][s][128] --------
__global__ __launch_bounds__(256) void rope_quant_kernel(
    const float* __restrict__ y, int8_t* __restrict__ o8,
    float* __restrict__ oscale, int doRope)
{
  const int gw = (blockIdx.x * 256 + threadIdx.x) >> 6;
  const int lane = threadIdx.x & 63;
  const int h = gw & (NHEAD - 1);
  const int tok = gw >> 5;
  const int s = tok & (S_LEN - 1);
  const float* yr = y + (size_t)tok * HDIM + h * DHEAD;
  float x0 = yr[lane], x1 = yr[lane + 64];
  float o0, o1;
  if (doRope) {
    const float e = (float)lane * (1.0f / 64.0f);
    const float inv = powf(10000.0f, -e);
    const float ang = (float)s * inv;
    float sn, c;
    sincosf(ang, &sn, &c);
    o0 = x0 * c - x1 * sn;
    o1 = x1 * c + x0 * sn;
  } else {
    o0 = x0; o1 = x1;
  }
  float am = fmaxf(fabsf(o0), fabsf(o1));
#pragma unroll
  for (int off = 32; off > 0; off >>= 1) am = fmaxf(am, __shfl_xor(am, off));
  const float scale = fmaxf(am / 127.0f, 1e-8f);
  const float q0 = fminf(fmaxf(rintf(o0 / scale), -128.f), 127.f);
  const float q1 = fminf(fmaxf(rintf(o1 / scale), -128.f), 127.f);
  const size_t orow = (size_t)((tok >> 10) * NHEAD + h) * S_LEN + s;
  int8_t* op = o8 + orow * DHEAD;
  op[lane] = (int8_t)(int)q0;
  op[lane + 64] = (int8_t)(int)q1;
  if (lane == 0) oscale[orow] = scale;
}

// -------- V: quant per (b,h,s) row, fold sv in, store TRANSPOSED bf16 [bh][d][s] --------
__global__ __launch_bounds__(256) void vtrans_kernel(
    const float* __restrict__ y, unsigned short* __restrict__ vqT)
{
  __shared__ unsigned short vt[128][80];
  const int tid = threadIdx.x;
  const int wv = tid >> 6, lane = tid & 63;
  const int bh = blockIdx.y, s0 = blockIdx.x * 64;
  const int b = bh >> 5, h = bh & 31;
  for (int it = 0; it < 16; ++it) {
    const int tl = wv * 16 + it;
    const float* yr = y + ((size_t)(b * S_LEN + s0 + tl)) * HDIM + h * DHEAD;
    float x0 = yr[lane], x1 = yr[lane + 64];
    float am = fmaxf(fabsf(x0), fabsf(x1));
#pragma unroll
    for (int off = 32; off > 0; off >>= 1) am = fmaxf(am, __shfl_xor(am, off));
    const float scale = fmaxf(am / 127.0f, 1e-8f);
    const float q0 = fminf(fmaxf(rintf(x0 / scale), -128.f), 127.f);
    const float q1 = fminf(fmaxf(rintf(x1 / scale), -128.f), 127.f);
    vt[lane][tl] = f2bf(q0 * scale);      // sv folded into V (bf16)
    vt[lane + 64][tl] = f2bf(q1 * scale);
  }
  __syncthreads();
  const int d = tid >> 1, half = tid & 1;
  unsigned short* op = vqT + ((size_t)bh * 128 + d) * S_LEN + s0 + half * 32;
#pragma unroll
  for (int c = 0; c < 4; ++c)
    *(i32x4*)(op + c * 8) = *(const i32x4*)(&vt[d][half * 32 + c * 8]);
}

// -------- MFMA flash attention, causal-balanced: block does q-tiles (bx, 15-bx) --------
#define QB 64
#define KB 64

__global__ __launch_bounds__(256) void attn_mfma_kernel(
    const int8_t* __restrict__ qq, const float* __restrict__ sq,
    const int8_t* __restrict__ kq, const float* __restrict__ sk,
    const unsigned short* __restrict__ vqT,   // bf16 bits, sv pre-folded
    float* __restrict__ attn)
{
  __shared__ __align__(16) int8_t ks[KB * 128];
  __shared__ __align__(16) unsigned short vs[128 * 64];
  __shared__ __align__(16) unsigned short ps[QB][64];
  __shared__ float sk_t[KB];

  const int tid = threadIdx.x;
  const int w = tid >> 6;
  const int l = tid & 63;
  const int l15 = l & 15;
  const int lg = l >> 4;
  const int lr = l >> 3, g7 = l & 7;
  const int bh = blockIdx.y;
  const size_t bhS = (size_t)bh * S_LEN;
  const int b = bh >> 5, h = bh & 31;
  const int NT = S_LEN / QB;   // 16

  for (int rep = 0; rep < 2; ++rep) {
    const int qt = rep ? (NT - 1 - (int)blockIdx.x) : (int)blockIdx.x;
    const int q0 = qt * QB;
    const int nkt = qt + 1;

    const int qrow = q0 + w * 16 + l15;
    const int8_t* qp = qq + (bhS + qrow) * (size_t)DHEAD;
    const i32x4 qa0 = *(const i32x4*)(qp + lg * 16);
    const i32x4 qa1 = *(const i32x4*)(qp + 64 + lg * 16);

    float sqv[4];
    int qg[4];
#pragma unroll
    for (int r = 0; r < 4; ++r) {
      qg[r] = q0 + w * 16 + lg * 4 + r;
      sqv[r] = sq[bhS + qg[r]] * 0.08838834764831843f * 1.4426950408889634f;
    }

    float rmax[4] = {-3.0e38f, -3.0e38f, -3.0e38f, -3.0e38f};

    // ---------- pass 1: exact row max (log2 domain) ----------
    for (int kt = 0; kt < nkt; ++kt) {
      const int k0 = kt * KB;
#pragma unroll
      for (int i = 0; i < 2; ++i) {
        const int r0 = w * 16 + i * 8;
        gl2lds16(kq + (bhS + k0 + r0 + lr) * (size_t)128 + ((g7 ^ lr) << 4),
                 ks + r0 * 128);
      }
      if (tid < KB) sk_t[tid] = sk[bhS + k0 + tid];
      __syncthreads();
      const bool diag = (kt == nkt - 1);
#pragma unroll
      for (int c = 0; c < 4; ++c) {
        const int krow = c * 16 + l15;
        const i32x4 b0 = *(const i32x4*)(ks + krow * 128 + ((lg ^ (krow & 7)) << 4));
        const i32x4 b1 = *(const i32x4*)(ks + krow * 128 + (((lg + 4) ^ (krow & 7)) << 4));
        i32x4 acc = {0, 0, 0, 0};
        acc = __builtin_amdgcn_mfma_i32_16x16x64_i8(qa0, b0, acc, 0, 0, 0);
        acc = __builtin_amdgcn_mfma_i32_16x16x64_i8(qa1, b1, acc, 0, 0, 0);
        const float skv = sk_t[krow];
        const int kgl = k0 + krow;
#pragma unroll
        for (int r = 0; r < 4; ++r) {
          const float s = (float)acc[r] * sqv[r] * skv;
          if (!diag || (kgl <= qg[r])) rmax[r] = fmaxf(rmax[r], s);
        }
      }
      __syncthreads();
    }
#pragma unroll
    for (int r = 0; r < 4; ++r)
#pragma unroll
      for (int off = 1; off < 16; off <<= 1)
        rmax[r] = fmaxf(rmax[r], __shfl_xor(rmax[r], off));

    // ---------- pass 2: P quant + PV ----------
    float rs[4] = {0.f, 0.f, 0.f, 0.f};
    f32x4 oacc[8];
#pragma unroll
    for (int ds = 0; ds < 8; ++ds) oacc[ds] = (f32x4){0.f, 0.f, 0.f, 0.f};

    const int qloc = w * 16 + l15;
    const int swA0 = (lg ^ (qloc & 7)) << 3;
    const int swA1 = ((lg + 4) ^ (qloc & 7)) << 3;

    for (int kt = 0; kt < nkt; ++kt) {
      const int k0 = kt * KB;
#pragma unroll
      for (int i = 0; i < 2; ++i) {
        const int r0 = w * 16 + i * 8;
        gl2lds16(kq + (bhS + k0 + r0 + lr) * (size_t)128 + ((g7 ^ lr) << 4),
                 ks + r0 * 128);
      }
#pragma unroll
      for (int i = 0; i < 4; ++i) {
        const int r0 = w * 32 + i * 8;
        const unsigned short* src = vqT + ((size_t)bh * 128 + r0 + lr) * S_LEN
                                        + k0 + ((g7 ^ lr) << 3);
        gl2lds16(src, vs + r0 * 64);
      }
      if (tid < KB) sk_t[tid] = sk[bhS + k0 + tid];
      __syncthreads();
      const bool diag = (kt == nkt - 1);

#pragma unroll
      for (int c = 0; c < 4; ++c) {
        const int krow = c * 16 + l15;
        const i32x4 b0 = *(const i32x4*)(ks + krow * 128 + ((lg ^ (krow & 7)) << 4));
        const i32x4 b1 = *(const i32x4*)(ks + krow * 128 + (((lg + 4) ^ (krow & 7)) << 4));
        i32x4 acc = {0, 0, 0, 0};
        acc = __builtin_amdgcn_mfma_i32_16x16x64_i8(qa0, b0, acc, 0, 0, 0);
        acc = __builtin_amdgcn_mfma_i32_16x16x64_i8(qa1, b1, acc, 0, 0, 0);
        const float skv = sk_t[krow];
        const int kgl = k0 + krow;
#pragma unroll
        for (int r = 0; r < 4; ++r) {
          const float s2 = (float)acc[r] * sqv[r] * skv;
          const bool valid = !diag || (kgl <= qg[r]);
          const float e = valid ? exp2f(s2 - rmax[r]) : 0.0f;
          rs[r] += e;
          const float p = rintf(e * 127.0f);
          const int qr = w * 16 + lg * 4 + r;
          const int sidx = (((krow >> 3) ^ (qr & 7)) << 3) | (krow & 7);
          ps[qr][sidx] = f2bf(p);
        }
      }

      const bf16x8 a0 = *(const bf16x8*)&ps[qloc][swA0];
      const bf16x8 a1 = *(const bf16x8*)&ps[qloc][swA1];
#pragma unroll
      for (int ds = 0; ds < 8; ++ds) {
        const int d = ds * 16 + l15;
        const bf16x8 bv0 = *(const bf16x8*)(vs + d * 64 + ((lg ^ (d & 7)) << 3));
        const bf16x8 bv1 = *(const bf16x8*)(vs + d * 64 + (((lg + 4) ^ (d & 7)) << 3));
        oacc[ds] = __builtin_amdgcn_mfma_f32_16x16x32_bf16(a0, bv0, oacc[ds], 0, 0, 0);
        oacc[ds] = __builtin_amdgcn_mfma_f32_16x16x32_bf16(a1, bv1, oacc[ds], 0, 0, 0);
      }
      __syncthreads();
    }

    // ---------- epilogue ----------
#pragma unroll
    for (int r = 0; r < 4; ++r)
#pragma unroll
      for (int off = 1; off < 16; off <<= 1)
        rs[r] += __shfl_xor(rs[r], off);

#pragma unroll
    for (int r = 0; r < 4; ++r) {
      const float inv = 1.0f / (127.0f * rs[r]);
      float* op = attn + ((size_t)(b * S_LEN + qg[r])) * HDIM + h * DHEAD + l15;
#pragma unroll
      for (int ds = 0; ds < 8; ++ds)
        op[ds * 16] = oacc[ds][r] * inv;
    }
  }
}

extern "C" void kernel_launch(void* const* d_in, const int* in_sizes, int n_in,
                              void* d_out, int out_size, void* d_ws, size_t ws_size,
                              hipStream_t stream) {
  const float* hs = (const float*)d_in[0];
  const float* wmat[4] = { (const float*)d_in[1], (const float*)d_in[2],
                           (const float*)d_in[3], (const float*)d_in[4] };

  char* p = (char*)d_ws;
  auto take = [&](size_t sz) { char* r = p; p += (sz + 255) & ~(size_t)255; return r; };

  int8_t* xq8 = (int8_t*)take((size_t)MTOK * HDIM);
  int8_t* w4[4];
  for (int i = 0; i < 4; ++i) w4[i] = (int8_t*)take((size_t)HDIM * HDIM);
  float* sx = (float*)take((size_t)MTOK * 4);
  float* sw[4];
  for (int i = 0; i < 4; ++i) sw[i] = (float*)take((size_t)HDIM * 4);
  float* y = (float*)take((size_t)MTOK * HDIM * 4);
  int8_t* qq8 = (int8_t*)take((size_t)MTOK * HDIM);
  int8_t* kq8 = (int8_t*)take((size_t)MTOK * HDIM);
  unsigned short* vqT = (unsigned short*)take((size_t)MTOK * HDIM * 2);
  float* sqs = (float*)take((size_t)BATCH * NHEAD * S_LEN * 4);
  float* sks = (float*)take((size_t)BATCH * NHEAD * S_LEN * 4);
  float* sattn = (float*)take((size_t)MTOK * 4);

  rowquant_kernel<<<MTOK, 256, 0, stream>>>(hs, xq8, sx, 127.f, -128.f);
  for (int i = 0; i < 4; ++i)
    rowquant_kernel<<<HDIM, 256, 0, stream>>>(wmat[i], w4[i], sw[i], 7.f, -8.f);

  const dim3 gg(HDIM / BN, MTOK / BM);  // (16,16) = 256 blocks
  gemm_i8_mfma2_kernel<<<gg, 512, 0, stream>>>(xq8, sx, w4[0], sw[0], y);
  rope_quant_kernel<<<MTOK * NHEAD / 4, 256, 0, stream>>>(y, qq8, sqs, 1);
  gemm_i8_mfma2_kernel<<<gg, 512, 0, stream>>>(xq8, sx, w4[1], sw[1], y);
  rope_quant_kernel<<<MTOK * NHEAD / 4, 256, 0, stream>>>(y, kq8, sks, 1);
  gemm_i8_mfma2_kernel<<<gg, 512, 0, stream>>>(xq8, sx, w4[2], sw[2], y);
  vtrans_kernel<<<dim3(S_LEN / 64, BATCH * NHEAD), 256, 0, stream>>>(y, vqT);

  attn_mfma_kernel<<<dim3(S_LEN / QB / 2, BATCH * NHEAD), 256, 0, stream>>>(
      qq8, sqs, kq8, sks, vqT, y);

  rowquant_kernel<<<MTOK, 256, 0, stream>>>(y, xq8, sattn, 127.f, -128.f);
  gemm_i8_mfma2_kernel<<<gg, 512, 0, stream>>>(xq8, sattn, w4[3], sw[3], (float*)d_out);
}